// Round 1
// baseline (279.340 us; speedup 1.0000x reference)
//
#include <hip/hip_runtime.h>
#include <hip/hip_bf16.h>
#include <stdint.h>

#define HW_ 4096

typedef float f32x4 __attribute__((ext_vector_type(4)));
typedef short bf16x8 __attribute__((ext_vector_type(8)));

__device__ __forceinline__ unsigned short f2bf(float f) {
  __hip_bfloat16 h = __float2bfloat16(f);
  return *reinterpret_cast<unsigned short*>(&h);
}
__device__ __forceinline__ float sigmoidf_(float x) { return 1.f / (1.f + __expf(-x)); }

__device__ __forceinline__ void glds16(const void* g, void* l) {
  __builtin_amdgcn_global_load_lds(
      (const __attribute__((address_space(1))) unsigned int*)g,
      (__attribute__((address_space(3))) unsigned int*)l, 16, 0, 0);
}

// ---------------- 1. per-(b,c) mean + max over H*W ----------------
__global__ void k_reduce(const float* __restrict__ x, float* __restrict__ gap,
                         float* __restrict__ xmax) {
  int bc = blockIdx.x;
  const float4* p4 = reinterpret_cast<const float4*>(x + (size_t)bc * HW_);
  int t = threadIdx.x;
  float s = 0.f, m = -3.4e38f;
  for (int i = t; i < HW_ / 4; i += 256) {
    float4 v = p4[i];
    s += (v.x + v.y) + (v.z + v.w);
    m = fmaxf(m, fmaxf(fmaxf(v.x, v.y), fmaxf(v.z, v.w)));
  }
  __shared__ float ss[256], sm[256];
  ss[t] = s; sm[t] = m; __syncthreads();
  for (int off = 128; off > 0; off >>= 1) {
    if (t < off) { ss[t] += ss[t + off]; sm[t] = fmaxf(sm[t], sm[t + off]); }
    __syncthreads();
  }
  if (t == 0) { gap[bc] = ss[0] * (1.f / HW_); xmax[bc] = sm[0]; }
}

// ---------------- 2. all the small per-batch math ----------------
__global__ void k_tiny(const float* __restrict__ gap, const float* __restrict__ xmax,
                       const float* __restrict__ aw3, const float* __restrict__ Wout,
                       const float* __restrict__ Wk, const float* __restrict__ lw3,
                       const float* __restrict__ lbia, const float* __restrict__ mw1,
                       const float* __restrict__ mw2,
                       float* __restrict__ in_att, float* __restrict__ out_att,
                       float* __restrict__ katt, float* __restrict__ sc,
                       float* __restrict__ zerob) {
  int b = blockIdx.x, t = threadIdx.x;
  __shared__ float g[256], tt[256], red[256], hsum[16], ksm[4], mx[128];
  g[t] = gap[b * 256 + t];
  if (b == 0 && t < 4) zerob[t] = 0.f;
  __syncthreads();
  float c0 = aw3[0], c1 = aw3[1], c2 = aw3[2];
  float tv = c1 * g[t];
  if (t > 0) tv += c0 * g[t - 1];
  if (t < 255) tv += c2 * g[t + 1];
  tt[t] = tv;
  in_att[b * 256 + t] = sigmoidf_(tv);
  __syncthreads();
  // out_att = sigmoid(t @ Wout^T)
  {
    float d = 0.f;
    const float* wr = Wout + (size_t)t * 256;
    for (int c = 0; c < 256; ++c) d += tt[c] * wr[c];
    out_att[b * 256 + t] = sigmoidf_(d);
  }
  // k_att = softmax(t @ Wk^T)
  int k = t >> 6, lane = t & 63;
  {
    float pk = 0.f;
    for (int c = lane; c < 256; c += 64) pk += tt[c] * Wk[k * 256 + c];
    red[t] = pk; __syncthreads();
    for (int off = 32; off > 0; off >>= 1) {
      if (lane < off) red[t] += red[t + off];
      __syncthreads();
    }
    if (t == 0) {
      float l0 = red[0], l1 = red[64], l2 = red[128], l3 = red[192];
      float mm = fmaxf(fmaxf(l0, l1), fmaxf(l2, l3));
      float e0 = __expf(l0 - mm), e1 = __expf(l1 - mm), e2 = __expf(l2 - mm), e3 = __expf(l3 - mm);
      float inv = 1.f / (e0 + e1 + e2 + e3);
      ksm[0] = e0 * inv; ksm[1] = e1 * inv; ksm[2] = e2 * inv; ksm[3] = e3 * inv;
    }
    __syncthreads();
    if (t < 4) katt[b * 4 + t] = ksm[t];
  }
  // lga first-half scale: conv1d over gap[:,:128] (zero pad at 0 and 127!)
  if (t < 128) {
    float a0 = lw3[0], a1 = lw3[1], a2 = lw3[2];
    float sv = a1 * g[t] + lbia[0];
    if (t > 0) sv += a0 * g[t - 1];
    if (t < 127) sv += a2 * g[t + 1];
    sc[b * 256 + t] = sigmoidf_(sv);
    mx[t] = xmax[b * 256 + 128 + t];
  }
  __syncthreads();
  if (t < 16) {
    float d1 = 0.f, d2 = 0.f;
    const float* w1r = mw1 + t * 128;
    for (int j = 0; j < 128; ++j) { d1 += mx[j] * w1r[j]; d2 += g[128 + j] * w1r[j]; }
    hsum[t] = fmaxf(d1, 0.f) + fmaxf(d2, 0.f);
  }
  __syncthreads();
  if (t < 128) {
    float dd = 0.f;
    const float* w2r = mw2 + t * 16;
    for (int r = 0; r < 16; ++r) dd += hsum[r] * w2r[r];
    sc[b * 256 + 128 + t] = sigmoidf_(dd);
  }
}

// ---------------- 3. x_mod = x*in_att, transpose to [b][hw][c] bf16 ----------------
__global__ void k_xt(const float* __restrict__ x, const float* __restrict__ in_att,
                     unsigned short* __restrict__ xt) {
  int hwb = blockIdx.x;  // 64 hw per block
  int cb = blockIdx.y;   // 64 c per block
  int b = blockIdx.z;
  int t = threadIdx.x;
  __shared__ unsigned short lt[64][66];
  int c_l0 = t >> 6;
  int hw_l = t & 63;
#pragma unroll
  for (int i = 0; i < 16; ++i) {
    int c_l = i * 4 + c_l0;
    int c = cb * 64 + c_l;
    float v = x[(((size_t)b * 256 + c) << 12) + hwb * 64 + hw_l] * in_att[b * 256 + c];
    lt[hw_l][c_l] = f2bf(v);
  }
  __syncthreads();
#pragma unroll
  for (int i = 0; i < 8; ++i) {
    int fp = t + i * 256;
    int hw2 = fp >> 5;
    int cp = (fp & 31) * 2;
    unsigned int u = (unsigned int)lt[hw2][cp] | ((unsigned int)lt[hw2][cp + 1] << 16);
    *reinterpret_cast<unsigned int*>(xt + (((size_t)b * 4096 + hwb * 64 + hw2) << 8) + cb * 64 + cp) = u;
  }
}

// ---------------- 4. aggregate bank weights with k_att, to bf16 ----------------
// agg[((b*256+o)*9+pq)*256 + i]
__global__ void k_agg(const float* __restrict__ ede, const float* __restrict__ katt,
                      unsigned short* __restrict__ agg) {
  long long idx = (long long)blockIdx.x * 256 + threadIdx.x;  // 4,718,592 total
  int i = (int)((idx & 127) * 2);
  long long rest = idx >> 7;           // (b*256+o)*9+pq
  int pq = (int)(rest % 9);
  long long bo = rest / 9;
  int o = (int)(bo & 255);
  int b = (int)(bo >> 8);
  float k0 = katt[b * 4], k1 = katt[b * 4 + 1], k2 = katt[b * 4 + 2], k3 = katt[b * 4 + 3];
  const long long S = 256LL * 256 * 9;
  long long base = ((long long)o * 256 + i) * 9 + pq;
  float v0 = k0 * ede[base] + k1 * ede[base + S] + k2 * ede[base + 2 * S] + k3 * ede[base + 3 * S];
  float v1 = k0 * ede[base + 9] + k1 * ede[base + S + 9] + k2 * ede[base + 2 * S + 9] + k3 * ede[base + 3 * S + 9];
  unsigned int u = (unsigned int)f2bf(v0) | ((unsigned int)f2bf(v1) << 16);
  *reinterpret_cast<unsigned int*>(agg + ((bo * 9 + pq) << 8) + i) = u;
}

// ---------------- 5. implicit-GEMM conv + fused epilogue (Q*out_att + K) ----------------
__global__ __launch_bounds__(256) void k_conv(
    const unsigned short* __restrict__ agg, const unsigned short* __restrict__ xt,
    const float* __restrict__ x, const float* __restrict__ oatt,
    const float* __restrict__ sc, const float* __restrict__ zerob,
    float* __restrict__ zout) {
  int rt = blockIdx.x;  // 32 pixel tiles (128 px = 2 image rows)
  int ot = blockIdx.y;  // 2 out-channel tiles
  int b = blockIdx.z;   // 16
  int tid = threadIdx.x;
  int wv = tid >> 6, l = tid & 63;
  __shared__ __align__(16) char smem[16384];  // lA [0,8K), lB [8K,16K)
  char* lAc = smem;
  char* lBc = smem + 8192;

  // staging geometry: row = wv*32 + j*16 + (l>>2), 16B col slot = l&3 (XOR-swizzled)
  int srow0 = wv * 32 + (l >> 2);
  int srow1 = srow0 + 16;
  int slot = l & 3;
  int csw0 = (slot ^ ((srow0 >> 1) & 3)) * 8;  // element offset within 32-elem chunk
  int csw1 = (slot ^ ((srow1 >> 1) & 3)) * 8;
  long long arowbase0 = ((long long)(b * 256 + ot * 128 + srow0) * 9) * 256;
  long long arowbase1 = ((long long)(b * 256 + ot * 128 + srow1) * 9) * 256;
  int pix0 = rt * 128 + srow0;
  int pix1 = rt * 128 + srow1;
  int h0 = pix0 >> 6, xw0 = pix0 & 63;
  int h1 = pix1 >> 6, xw1 = pix1 & 63;
  int ldst0 = wv * 2048;
  int ldst1 = wv * 2048 + 1024;

  // fragment geometry
  int wm = wv >> 1, wn = wv & 1;
  int swz = ((l & 15) >> 1) & 3;
  int acol = ((l >> 4) ^ swz) * 16;
  int abase = (wm * 64 + (l & 15)) * 64 + acol;
  int bbase = (wn * 64 + (l & 15)) * 64 + acol;

  f32x4 zero4 = {0.f, 0.f, 0.f, 0.f};
  f32x4 acc[4][4];
#pragma unroll
  for (int i2 = 0; i2 < 4; ++i2)
#pragma unroll
    for (int j2 = 0; j2 < 4; ++j2) acc[i2][j2] = zero4;

  for (int pq = 0; pq < 9; ++pq) {
    int dp = pq / 3 - 1, dq = pq % 3 - 1;
    const unsigned short* ga0 = agg + arowbase0 + (long long)pq * 256 + csw0;
    const unsigned short* ga1 = agg + arowbase1 + (long long)pq * 256 + csw1;
    int hh0 = h0 + dp, ww0 = xw0 + dq;
    int hh1 = h1 + dp, ww1 = xw1 + dq;
    bool ok0 = ((unsigned)hh0 < 64u) && ((unsigned)ww0 < 64u);
    bool ok1 = ((unsigned)hh1 < 64u) && ((unsigned)ww1 < 64u);
    const unsigned short* gb0 =
        ok0 ? xt + (((long long)b * 4096 + hh0 * 64 + ww0) << 8) + csw0
            : (const unsigned short*)zerob;
    const unsigned short* gb1 =
        ok1 ? xt + (((long long)b * 4096 + hh1 * 64 + ww1) << 8) + csw1
            : (const unsigned short*)zerob;
    int stp0 = ok0 ? 32 : 0;
    int stp1 = ok1 ? 32 : 0;
#pragma unroll
    for (int ic = 0; ic < 8; ++ic) {
      glds16(ga0 + ic * 32, lAc + ldst0);
      glds16(ga1 + ic * 32, lAc + ldst1);
      glds16(gb0 + ic * stp0, lBc + ldst0);
      glds16(gb1 + ic * stp1, lBc + ldst1);
      __syncthreads();
      bf16x8 af[4], bfv[4];
#pragma unroll
      for (int f = 0; f < 4; ++f) {
        af[f] = *reinterpret_cast<const bf16x8*>(lAc + abase + f * 1024);
        bfv[f] = *reinterpret_cast<const bf16x8*>(lBc + bbase + f * 1024);
      }
#pragma unroll
      for (int fm = 0; fm < 4; ++fm)
#pragma unroll
        for (int fn = 0; fn < 4; ++fn)
          acc[fm][fn] = __builtin_amdgcn_mfma_f32_16x16x32_bf16(af[fm], bfv[fn], acc[fm][fn], 0, 0, 0);
      __syncthreads();
    }
  }

  // epilogue: z = Q*out_att + x[oc]*sc[oc]  (channel shuffle oc = (gm&3)*64 + gm>>2)
#pragma unroll
  for (int fm = 0; fm < 4; ++fm) {
#pragma unroll
    for (int r = 0; r < 4; ++r) {
      int m = wm * 64 + fm * 16 + (l >> 4) * 4 + r;
      int gm = ot * 128 + m;
      int oc = ((gm & 3) << 6) | (gm >> 2);
      float oav = oatt[b * 256 + gm];
      float scv = sc[b * 256 + oc];
      const float* xrow = x + (((size_t)b * 256 + oc) << 12);
      float* zrow = zout + (((size_t)b * 256 + gm) << 12);
#pragma unroll
      for (int fn = 0; fn < 4; ++fn) {
        int n = wn * 64 + fn * 16 + (l & 15);
        int ghw = rt * 128 + n;
        zrow[ghw] = acc[fm][fn][r] * oav + xrow[ghw] * scv;
      }
    }
  }
}

// ---------------- 6. per-channel BN stats ----------------
__global__ void k_stats(const float* __restrict__ z, const float* __restrict__ gamma,
                        const float* __restrict__ beta, float* __restrict__ stats) {
  int c = blockIdx.x, t = threadIdx.x;
  float s = 0.f, s2 = 0.f;
  for (int b = 0; b < 16; ++b) {
    const float4* p = reinterpret_cast<const float4*>(z + (((size_t)b * 256 + c) << 12));
    for (int i = t; i < 1024; i += 256) {
      float4 v = p[i];
      s += (v.x + v.y) + (v.z + v.w);
      s2 += (v.x * v.x + v.y * v.y) + (v.z * v.z + v.w * v.w);
    }
  }
  __shared__ float ss[256], ss2[256];
  ss[t] = s; ss2[t] = s2; __syncthreads();
  for (int off = 128; off > 0; off >>= 1) {
    if (t < off) { ss[t] += ss[t + off]; ss2[t] += ss2[t + off]; }
    __syncthreads();
  }
  if (t == 0) {
    float mean = ss[0] * (1.f / 65536.f);
    float var = ss2[0] * (1.f / 65536.f) - mean * mean;
    float rstd = rsqrtf(var + 1e-5f);
    float scale = gamma[c] * rstd;
    stats[c] = scale;
    stats[256 + c] = beta[c] - mean * scale;
  }
}

// ---------------- 7. BN apply + ReLU (in place on d_out) ----------------
__global__ void k_apply(float* __restrict__ z, const float* __restrict__ stats) {
  int idx = blockIdx.x * 256 + threadIdx.x;
  for (int i = idx; i < 4194304; i += 4096 * 256) {
    int c = (i >> 10) & 255;
    float scale = stats[c], shift = stats[256 + c];
    float4* p = reinterpret_cast<float4*>(z) + i;
    float4 v = *p;
    v.x = fmaxf(v.x * scale + shift, 0.f);
    v.y = fmaxf(v.y * scale + shift, 0.f);
    v.z = fmaxf(v.z * scale + shift, 0.f);
    v.w = fmaxf(v.w * scale + shift, 0.f);
    *p = v;
  }
}

extern "C" void kernel_launch(void* const* d_in, const int* in_sizes, int n_in,
                              void* d_out, int out_size, void* d_ws, size_t ws_size,
                              hipStream_t stream) {
  (void)in_sizes; (void)n_in; (void)out_size; (void)ws_size;
  const float* x = (const float*)d_in[0];
  const float* aw3 = (const float*)d_in[1];
  const float* Wout = (const float*)d_in[2];
  const float* Wk = (const float*)d_in[3];
  const float* ede = (const float*)d_in[4];
  const float* lw3 = (const float*)d_in[5];
  const float* lbia = (const float*)d_in[6];
  const float* mw1 = (const float*)d_in[7];
  const float* mw2 = (const float*)d_in[8];
  const float* gamma = (const float*)d_in[9];
  const float* beta = (const float*)d_in[10];

  char* ws = (char*)d_ws;
  float* gap   = (float*)(ws + 0);        // 16KB
  float* xmax  = (float*)(ws + 16384);    // 16KB
  float* inatt = (float*)(ws + 32768);    // 16KB
  float* oatt  = (float*)(ws + 49152);    // 16KB
  float* katt  = (float*)(ws + 65536);    // 256B
  float* sc    = (float*)(ws + 65792);    // 16KB
  float* zerob = (float*)(ws + 82176);    // 16B
  float* stats = (float*)(ws + 82432);    // 2KB
  unsigned short* xt  = (unsigned short*)(ws + (1 << 20));               // 32MB
  unsigned short* agg = (unsigned short*)(ws + (1 << 20) + 33554432);    // 18.9MB
  float* z = (float*)d_out;

  k_reduce<<<4096, 256, 0, stream>>>(x, gap, xmax);
  k_tiny<<<16, 256, 0, stream>>>(gap, xmax, aw3, Wout, Wk, lw3, lbia, mw1, mw2,
                                 inatt, oatt, katt, sc, zerob);
  k_xt<<<dim3(64, 4, 16), 256, 0, stream>>>(x, inatt, xt);
  k_agg<<<18432, 256, 0, stream>>>(ede, katt, agg);
  k_conv<<<dim3(32, 2, 16), 256, 0, stream>>>(agg, xt, x, oatt, sc, zerob, z);
  k_stats<<<256, 256, 0, stream>>>(z, gamma, beta, stats);
  k_apply<<<4096, 256, 0, stream>>>(z, stats);
}

// Round 3
// 230.426 us; speedup vs baseline: 1.2123x; 1.2123x over previous
//
#include <hip/hip_runtime.h>
#include <hip/hip_bf16.h>
#include <stdint.h>

#define HW_ 4096

typedef float f32x4 __attribute__((ext_vector_type(4)));
typedef short bf16x8 __attribute__((ext_vector_type(8)));

__device__ __forceinline__ unsigned short f2bf(float f) {
  __hip_bfloat16 h = __float2bfloat16(f);
  return *reinterpret_cast<unsigned short*>(&h);
}
__device__ __forceinline__ float sigmoidf_(float x) { return 1.f / (1.f + __expf(-x)); }

__device__ __forceinline__ void glds16(const void* g, void* l) {
  __builtin_amdgcn_global_load_lds(
      (const __attribute__((address_space(1))) unsigned int*)g,
      (__attribute__((address_space(3))) unsigned int*)l, 16, 0, 0);
}

// ---------------- 1. per-(b,c) mean + max over H*W ----------------
__global__ void k_reduce(const float* __restrict__ x, float* __restrict__ gap,
                         float* __restrict__ xmax) {
  int bc = blockIdx.x;
  const float4* p4 = reinterpret_cast<const float4*>(x + (size_t)bc * HW_);
  int t = threadIdx.x;
  float s = 0.f, m = -3.4e38f;
  for (int i = t; i < HW_ / 4; i += 256) {
    float4 v = p4[i];
    s += (v.x + v.y) + (v.z + v.w);
    m = fmaxf(m, fmaxf(fmaxf(v.x, v.y), fmaxf(v.z, v.w)));
  }
  __shared__ float ss[256], sm[256];
  ss[t] = s; sm[t] = m; __syncthreads();
  for (int off = 128; off > 0; off >>= 1) {
    if (t < off) { ss[t] += ss[t + off]; sm[t] = fmaxf(sm[t], sm[t + off]); }
    __syncthreads();
  }
  if (t == 0) { gap[bc] = ss[0] * (1.f / HW_); xmax[bc] = sm[0]; }
}

// ---------------- 2. small per-batch math (+ zero BN accumulators + zero page) ------
__global__ void k_tiny(const float* __restrict__ gap, const float* __restrict__ xmax,
                       const float* __restrict__ aw3, const float* __restrict__ Wout,
                       const float* __restrict__ Wk, const float* __restrict__ lw3,
                       const float* __restrict__ lbia, const float* __restrict__ mw1,
                       const float* __restrict__ mw2,
                       float* __restrict__ in_att, float* __restrict__ out_att,
                       float* __restrict__ katt, float* __restrict__ sc,
                       float* __restrict__ sums, float* __restrict__ zerob) {
  int b = blockIdx.x, t = threadIdx.x;
  __shared__ float g[256], tt[256], red[256], hsum[16], ksm[4], mx[128];
  g[t] = gap[b * 256 + t];
  if (b == 0) {
    sums[t] = 0.f; sums[256 + t] = 0.f;
    if (t < 16) zerob[t] = 0.f;
  }
  __syncthreads();
  float c0 = aw3[0], c1 = aw3[1], c2 = aw3[2];
  float tv = c1 * g[t];
  if (t > 0) tv += c0 * g[t - 1];
  if (t < 255) tv += c2 * g[t + 1];
  tt[t] = tv;
  in_att[b * 256 + t] = sigmoidf_(tv);
  __syncthreads();
  {
    float d = 0.f;
    const float* wr = Wout + (size_t)t * 256;
    for (int c = 0; c < 256; ++c) d += tt[c] * wr[c];
    out_att[b * 256 + t] = sigmoidf_(d);
  }
  int k = t >> 6, lane = t & 63;
  {
    float pk = 0.f;
    for (int c = lane; c < 256; c += 64) pk += tt[c] * Wk[k * 256 + c];
    red[t] = pk; __syncthreads();
    for (int off = 32; off > 0; off >>= 1) {
      if (lane < off) red[t] += red[t + off];
      __syncthreads();
    }
    if (t == 0) {
      float l0 = red[0], l1 = red[64], l2 = red[128], l3 = red[192];
      float mm = fmaxf(fmaxf(l0, l1), fmaxf(l2, l3));
      float e0 = __expf(l0 - mm), e1 = __expf(l1 - mm), e2 = __expf(l2 - mm), e3 = __expf(l3 - mm);
      float inv = 1.f / (e0 + e1 + e2 + e3);
      ksm[0] = e0 * inv; ksm[1] = e1 * inv; ksm[2] = e2 * inv; ksm[3] = e3 * inv;
    }
    __syncthreads();
    if (t < 4) katt[b * 4 + t] = ksm[t];
  }
  if (t < 128) {
    float a0 = lw3[0], a1 = lw3[1], a2 = lw3[2];
    float sv = a1 * g[t] + lbia[0];
    if (t > 0) sv += a0 * g[t - 1];
    if (t < 127) sv += a2 * g[t + 1];
    sc[b * 256 + t] = sigmoidf_(sv);
    mx[t] = xmax[b * 256 + 128 + t];
  }
  __syncthreads();
  if (t < 16) {
    float d1 = 0.f, d2 = 0.f;
    const float* w1r = mw1 + t * 128;
    for (int j = 0; j < 128; ++j) { d1 += mx[j] * w1r[j]; d2 += g[128 + j] * w1r[j]; }
    hsum[t] = fmaxf(d1, 0.f) + fmaxf(d2, 0.f);
  }
  __syncthreads();
  if (t < 128) {
    float dd = 0.f;
    const float* w2r = mw2 + t * 16;
    for (int r = 0; r < 16; ++r) dd += hsum[r] * w2r[r];
    sc[b * 256 + 128 + t] = sigmoidf_(dd);
  }
}

// ---------------- 3. x_mod = x*in_att, transpose to [b][hw][c] bf16 ----------------
__global__ void k_xt(const float* __restrict__ x, const float* __restrict__ in_att,
                     unsigned short* __restrict__ xt) {
  int hwb = blockIdx.x;  // 64 hw per block
  int cb = blockIdx.y;   // 64 c per block
  int b = blockIdx.z;
  int t = threadIdx.x;
  __shared__ unsigned short lt[64][66];
  int c_l0 = t >> 6;
  int hw_l = t & 63;
#pragma unroll
  for (int i = 0; i < 16; ++i) {
    int c_l = i * 4 + c_l0;
    int c = cb * 64 + c_l;
    float v = x[(((size_t)b * 256 + c) << 12) + hwb * 64 + hw_l] * in_att[b * 256 + c];
    lt[hw_l][c_l] = f2bf(v);
  }
  __syncthreads();
#pragma unroll
  for (int i = 0; i < 8; ++i) {
    int fp = t + i * 256;
    int hw2 = fp >> 5;
    int cp = (fp & 31) * 2;
    unsigned int u = (unsigned int)lt[hw2][cp] | ((unsigned int)lt[hw2][cp + 1] << 16);
    *reinterpret_cast<unsigned int*>(xt + (((size_t)b * 4096 + hwb * 64 + hw2) << 8) + cb * 64 + cp) = u;
  }
}

// ---------------- 4. aggregate bank weights with k_att, to bf16 ----------------
// agg[(b*256+o)*2304 + pq*256 + i]
__global__ void k_agg(const float* __restrict__ ede, const float* __restrict__ katt,
                      unsigned short* __restrict__ agg) {
  long long idx = (long long)blockIdx.x * 256 + threadIdx.x;  // 4,718,592 total
  int i = (int)((idx & 127) * 2);
  long long rest = idx >> 7;           // (b*256+o)*9+pq
  int pq = (int)(rest % 9);
  long long bo = rest / 9;
  int o = (int)(bo & 255);
  int b = (int)(bo >> 8);
  float k0 = katt[b * 4], k1 = katt[b * 4 + 1], k2 = katt[b * 4 + 2], k3 = katt[b * 4 + 3];
  const long long S = 256LL * 256 * 9;
  long long base = ((long long)o * 256 + i) * 9 + pq;
  float v0 = k0 * ede[base] + k1 * ede[base + S] + k2 * ede[base + 2 * S] + k3 * ede[base + 3 * S];
  float v1 = k0 * ede[base + 9] + k1 * ede[base + S + 9] + k2 * ede[base + 2 * S + 9] + k3 * ede[base + 3 * S + 9];
  unsigned int u = (unsigned int)f2bf(v0) | ((unsigned int)f2bf(v1) << 16);
  *reinterpret_cast<unsigned int*>(agg + ((bo * 9 + pq) << 8) + i) = u;
}

// ---------------- 5. deep-pipelined implicit-GEMM conv, fused epilogue + BN partial sums ----
// BM=256 (all out-ch), BN=256 px, BK=32, 512 thr / 8 waves (2M x 4N), 4 LDS buffers (128KB),
// pipeline depth 3, counted vmcnt(8) (never 0 in main loop), setprio around MFMA cluster.
__global__ __launch_bounds__(512, 2) void k_conv(
    const unsigned short* __restrict__ agg, const unsigned short* __restrict__ xt,
    const float* __restrict__ x, const float* __restrict__ oatt,
    const float* __restrict__ sc, const float* __restrict__ zerob,
    float* __restrict__ sums, float* __restrict__ zout) {
  __shared__ __align__(16) char smem[131072];
  int wg = blockIdx.x;
  int bswz = ((wg & 7) << 5) | (wg >> 3);  // chunked XCD swizzle: 32 blocks (=2 batches)/XCD
  int b = bswz >> 4, pt = bswz & 15;       // pt: 256-px tile = image rows 4pt..4pt+3
  int tid = threadIdx.x;
  int l = tid & 63;
  int wv = tid >> 6;
  int wm = wv >> 2, wn = wv & 3;

  // ---- staging geometry (2 A-slots + 2 B-slots of 16B per thread per K-tile) ----
  int r0 = tid >> 2, s0 = tid & 3;   // LDS slot index = tid (slot0), tid+512 (slot1)
  int r1 = r0 + 128;
  int f0 = (s0 ^ ((r0 >> 1) & 3)) << 3;  // pre-swizzled source ch offset (elements)
  int f1 = (s0 ^ ((r1 >> 1) & 3)) << 3;
  const unsigned short* aS0 = agg + (size_t)(b * 256 + r0) * 2304 + f0;
  const unsigned short* aS1 = agg + (size_t)(b * 256 + r1) * 2304 + f1;
  int p0 = pt * 256 + r0, p1 = pt * 256 + r1;   // global pixel indices
  int h0 = p0 >> 6, w0 = p0 & 63;
  int h1 = p1 >> 6, w1 = p1 & 63;
  const unsigned short* bS0 = xt + (((size_t)b * 4096 + p0) << 8) + f0;
  const unsigned short* bS1 = xt + (((size_t)b * 4096 + p1) << 8) + f1;
  const unsigned short* zb = (const unsigned short*)zerob;
  char* aD0 = smem + tid * 16;
  char* aD1 = smem + tid * 16 + 8192;
  char* bD0 = smem + 16384 + tid * 16;
  char* bD1 = smem + 16384 + tid * 16 + 8192;

  // ---- fragment read offsets (swizzled) ----
  int aOff[8], bOff[4];
#pragma unroll
  for (int fm = 0; fm < 8; ++fm) {
    int R = wm * 128 + fm * 16 + (l & 15);
    aOff[fm] = R * 64 + (((l >> 4) ^ ((R >> 1) & 3)) << 4);
  }
#pragma unroll
  for (int fn = 0; fn < 4; ++fn) {
    int P = wn * 64 + fn * 16 + (l & 15);
    bOff[fn] = 16384 + P * 64 + (((l >> 4) ^ ((P >> 1) & 3)) << 4);
  }

  f32x4 acc[8][4];
  f32x4 zero4 = {0.f, 0.f, 0.f, 0.f};
#pragma unroll
  for (int i2 = 0; i2 < 8; ++i2)
#pragma unroll
    for (int j2 = 0; j2 < 4; ++j2) acc[i2][j2] = zero4;

  auto STAGE = [&](int k) {
    int bsel = (k & 3) << 15;
    int pq = k >> 3, cs = k & 7;
    int dp = (pq * 11) >> 5;             // pq/3
    int dq = pq - 3 * dp;
    glds16(aS0 + k * 32, aD0 + bsel);
    glds16(aS1 + k * 32, aD1 + bsel);
    int boff = ((dp - 1) * 64 + (dq - 1)) * 256 + cs * 32;
    int hh0 = h0 + dp - 1, ww0 = w0 + dq - 1;
    int hh1 = h1 + dp - 1, ww1 = w1 + dq - 1;
    bool ok0 = ((unsigned)hh0 < 64u) && ((unsigned)ww0 < 64u);
    bool ok1 = ((unsigned)hh1 < 64u) && ((unsigned)ww1 < 64u);
    glds16(ok0 ? (bS0 + boff) : zb, bD0 + bsel);
    glds16(ok1 ? (bS1 + boff) : zb, bD1 + bsel);
  };

  auto COMPUTE = [&](int k) {
    const char* base = smem + ((k & 3) << 15);
    bf16x8 af[8], bv[4];
#pragma unroll
    for (int fm = 0; fm < 8; ++fm) af[fm] = *reinterpret_cast<const bf16x8*>(base + aOff[fm]);
#pragma unroll
    for (int fn = 0; fn < 4; ++fn) bv[fn] = *reinterpret_cast<const bf16x8*>(base + bOff[fn]);
    __builtin_amdgcn_s_setprio(1);
#pragma unroll
    for (int fm = 0; fm < 8; ++fm)
#pragma unroll
      for (int fn = 0; fn < 4; ++fn)
        acc[fm][fn] = __builtin_amdgcn_mfma_f32_16x16x32_bf16(af[fm], bv[fn], acc[fm][fn], 0, 0, 0);
    __builtin_amdgcn_s_setprio(0);
  };

  // prologue: 3 tiles in flight
  STAGE(0); STAGE(1); STAGE(2);
  asm volatile("s_waitcnt vmcnt(8)" ::: "memory");  // KT0 landed (own)
  // main loop: 72 K-tiles of 32 (9 taps x 8 ch-steps)
  for (int kt = 0; kt < 69; ++kt) {
    __builtin_amdgcn_s_barrier();                    // all waves done reading buf[(kt+3)&3]
    STAGE(kt + 3);
    asm volatile("s_waitcnt vmcnt(8)" ::: "memory"); // retire own KT(kt+1)
    COMPUTE(kt);
  }
  __builtin_amdgcn_s_barrier();
  asm volatile("s_waitcnt vmcnt(4)" ::: "memory");
  COMPUTE(69);
  __builtin_amdgcn_s_barrier();
  asm volatile("s_waitcnt vmcnt(0)" ::: "memory");
  COMPUTE(70);
  __builtin_amdgcn_s_barrier();
  COMPUTE(71);
  __syncthreads();

  // ---- epilogue: z = Q*out_att + x[oc]*sc[oc]; fused BN partial sums ----
  float* ls = (float*)smem;  // [256] sum, [256] sumsq
  ls[tid] = 0.f;             // tid < 512 covers both halves
  __syncthreads();

#pragma unroll
  for (int fm = 0; fm < 8; ++fm) {
#pragma unroll
    for (int r = 0; r < 4; ++r) {
      int m = wm * 128 + fm * 16 + ((l >> 4) << 2) + r;
      int oc = ((m & 3) << 6) | (m >> 2);
      float oav = oatt[b * 256 + m];
      float scv = sc[b * 256 + oc];
      const float* xrow = x + (((size_t)b * 256 + oc) << 12) + pt * 256;
      float* zrow = zout + (((size_t)b * 256 + m) << 12) + pt * 256;
      float psum = 0.f, psum2 = 0.f;
#pragma unroll
      for (int fn = 0; fn < 4; ++fn) {
        int n = wn * 64 + fn * 16 + (l & 15);
        float zv = acc[fm][fn][r] * oav + xrow[n] * scv;
        zrow[n] = zv;
        psum += zv; psum2 += zv * zv;
      }
#pragma unroll
      for (int d = 8; d > 0; d >>= 1) {
        psum += __shfl_down(psum, d, 16);
        psum2 += __shfl_down(psum2, d, 16);
      }
      if ((l & 15) == 0) {
        atomicAdd(&ls[m], psum);
        atomicAdd(&ls[256 + m], psum2);
      }
    }
  }
  __syncthreads();
  if (tid < 256) {
    atomicAdd(&sums[tid], ls[tid]);
    atomicAdd(&sums[256 + tid], ls[256 + tid]);
  }
}

// ---------------- 6. BN finalize + apply + ReLU (in place on d_out) ----------------
__global__ void k_apply(float* __restrict__ z, const float* __restrict__ sums,
                        const float* __restrict__ gamma, const float* __restrict__ beta) {
  int idx = blockIdx.x * 256 + threadIdx.x;
  for (int i = idx; i < 4194304; i += 4096 * 256) {
    int c = (i >> 10) & 255;
    float mean = sums[c] * (1.f / 65536.f);
    float var = sums[256 + c] * (1.f / 65536.f) - mean * mean;
    float scale = gamma[c] * rsqrtf(var + 1e-5f);
    float shift = beta[c] - mean * scale;
    float4* p = reinterpret_cast<float4*>(z) + i;
    float4 v = *p;
    v.x = fmaxf(v.x * scale + shift, 0.f);
    v.y = fmaxf(v.y * scale + shift, 0.f);
    v.z = fmaxf(v.z * scale + shift, 0.f);
    v.w = fmaxf(v.w * scale + shift, 0.f);
    *p = v;
  }
}

extern "C" void kernel_launch(void* const* d_in, const int* in_sizes, int n_in,
                              void* d_out, int out_size, void* d_ws, size_t ws_size,
                              hipStream_t stream) {
  (void)in_sizes; (void)n_in; (void)out_size; (void)ws_size;
  const float* x = (const float*)d_in[0];
  const float* aw3 = (const float*)d_in[1];
  const float* Wout = (const float*)d_in[2];
  const float* Wk = (const float*)d_in[3];
  const float* ede = (const float*)d_in[4];
  const float* lw3 = (const float*)d_in[5];
  const float* lbia = (const float*)d_in[6];
  const float* mw1 = (const float*)d_in[7];
  const float* mw2 = (const float*)d_in[8];
  const float* gamma = (const float*)d_in[9];
  const float* beta = (const float*)d_in[10];

  char* ws = (char*)d_ws;
  float* gap   = (float*)(ws + 0);        // 16KB
  float* xmax  = (float*)(ws + 16384);    // 16KB
  float* inatt = (float*)(ws + 32768);    // 16KB
  float* oatt  = (float*)(ws + 49152);    // 16KB
  float* katt  = (float*)(ws + 65536);    // 256B
  float* sc    = (float*)(ws + 65792);    // 16KB
  float* zerob = (float*)(ws + 82176);    // 64B zero page
  float* sums  = (float*)(ws + 82432);    // 2KB BN accumulators
  unsigned short* xt  = (unsigned short*)(ws + 262144);               // 32MB
  unsigned short* agg = (unsigned short*)(ws + 262144 + 33554432);    // 18.9MB -> ends 50.3MiB
  float* z = (float*)d_out;

  k_reduce<<<4096, 256, 0, stream>>>(x, gap, xmax);
  k_tiny<<<16, 256, 0, stream>>>(gap, xmax, aw3, Wout, Wk, lw3, lbia, mw1, mw2,
                                 inatt, oatt, katt, sc, sums, zerob);
  k_xt<<<dim3(64, 4, 16), 256, 0, stream>>>(x, inatt, xt);
  k_agg<<<18432, 256, 0, stream>>>(ede, katt, agg);
  k_conv<<<256, 512, 0, stream>>>(agg, xt, x, oatt, sc, zerob, sums, z);
  k_apply<<<4096, 256, 0, stream>>>(z, sums, gamma, beta);
}